// Round 1
// baseline (2812.693 us; speedup 1.0000x reference)
//
#include <hip/hip_runtime.h>
#include <math.h>

// ---------------------------------------------------------------------------
// Kernel A: 3x3 conv (no pad) + bias + BN + ReLU, implicit GEMM.
// Block: 256 threads. Tile: 64 couts x 64 pixels, one batch sample.
// Per-thread: 4 couts x 4 pixels. K-chunks of 8 input channels staged in LDS.
// grid = (ceil(P/64), 4, 64)
// ---------------------------------------------------------------------------
__global__ __launch_bounds__(256) void cbr3x3_kernel(
    const float* __restrict__ x,      // (64,256,H,W)
    const float* __restrict__ w,      // (256,256,3,3)
    const float* __restrict__ bias,   // (256)
    const float* __restrict__ gam, const float* __restrict__ bet,
    const float* __restrict__ mu,  const float* __restrict__ var,
    float* __restrict__ out,          // (64,256,H-2,W-2)
    int H, int W)
{
    const int HW = H * W;
    const int Ho = H - 2, Wo = W - 2;
    const int P  = Ho * Wo;
    const int b   = blockIdx.z;
    const int co0 = blockIdx.y * 64;
    const int tid = threadIdx.x;
    const int pg  = tid & 15;   // pixel group: pixels pg*4 .. pg*4+3
    const int cg  = tid >> 4;   // cout group:  couts  cg*4 .. cg*4+3

    __shared__ __align__(16) float xs[8 * 961];    // 8 cin planes (up to 31x31)
    __shared__ __align__(16) float wsT[72 * 64];   // [cin*9+k][cout]  (transposed)

    const int p0 = blockIdx.x * 64 + pg * 4;
    int ro0[4];
    bool pv[4];
    #pragma unroll
    for (int j = 0; j < 4; ++j) {
        int p = p0 + j;
        pv[j] = (p < P);
        int pp = pv[j] ? p : 0;
        int py = pp / Wo, px = pp % Wo;
        ro0[j] = py * W + px;   // top-left of the 3x3 window in the input plane
    }

    float acc[4][4];
    #pragma unroll
    for (int i = 0; i < 4; ++i)
        #pragma unroll
        for (int j = 0; j < 4; ++j) acc[i][j] = 0.0f;

    for (int c0 = 0; c0 < 256; c0 += 8) {
        // stage 8 input-channel planes (contiguous in global)
        const float* xg = x + ((size_t)(b * 256 + c0)) * HW;
        for (int i = tid; i < 8 * HW; i += 256) xs[i] = xg[i];
        // stage weights transposed: wsT[r][co], r = ci_local*9 + k
        const float* wg = w + (size_t)c0 * 9;
        for (int i = tid; i < 72 * 64; i += 256) {
            int co = i & 63, r = i >> 6;
            wsT[r * 64 + co] = wg[(size_t)(co0 + co) * 2304 + r];
        }
        __syncthreads();

        #pragma unroll 2
        for (int ci = 0; ci < 8; ++ci) {
            const int cibase = ci * HW;
            #pragma unroll
            for (int ky = 0; ky < 3; ++ky) {
                const int rbase = cibase + ky * W;
                #pragma unroll
                for (int kx = 0; kx < 3; ++kx) {
                    const float4 wv = *(const float4*)(wsT + (ci * 9 + ky * 3 + kx) * 64 + cg * 4);
                    float xv[4];
                    #pragma unroll
                    for (int j = 0; j < 4; ++j) xv[j] = xs[rbase + ro0[j] + kx];
                    #pragma unroll
                    for (int j = 0; j < 4; ++j) {
                        acc[0][j] = fmaf(wv.x, xv[j], acc[0][j]);
                        acc[1][j] = fmaf(wv.y, xv[j], acc[1][j]);
                        acc[2][j] = fmaf(wv.z, xv[j], acc[2][j]);
                        acc[3][j] = fmaf(wv.w, xv[j], acc[3][j]);
                    }
                }
            }
        }
        __syncthreads();
    }

    // epilogue: y = conv + bias; out = relu(y*A + (be - mu*A)) = relu(conv*A + (bias-mu)*A + be)
    #pragma unroll
    for (int i = 0; i < 4; ++i) {
        const int co = co0 + cg * 4 + i;
        const float A   = gam[co] * rsqrtf(var[co] + 1e-5f);
        const float OFF = fmaf(bias[co] - mu[co], A, bet[co]);
        #pragma unroll
        for (int j = 0; j < 4; ++j) {
            if (pv[j]) {
                float r = fmaxf(fmaf(acc[i][j], A, OFF), 0.0f);
                out[((size_t)(b * 256 + co)) * P + p0 + j] = r;
            }
        }
    }
}

// ---------------------------------------------------------------------------
// Kernel B: fused 3-scale depthwise cross-correlation.
// One block per (b,c). Search plane (29x29) staged zero-padded (+2) in LDS;
// computes lc (7x7 tmpl, pad 2 -> 27x27), mc (5x5, pad 0 -> 25x25),
// sc (3x3, pad 0 -> 27x27).
// grid = (256, 64)
// ---------------------------------------------------------------------------
__global__ __launch_bounds__(256) void corr_kernel(
    const float* __restrict__ lf, const float* __restrict__ mf,
    const float* __restrict__ sf, const float* __restrict__ s,
    float* __restrict__ lc, float* __restrict__ mc, float* __restrict__ sc)
{
    const int c = blockIdx.x, b = blockIdx.y;
    const int bc = b * 256 + c;
    const int tid = threadIdx.x;
    __shared__ float sp[33 * 33];
    __shared__ float tl[49], tm[25], ts[9];

    for (int i = tid; i < 33 * 33; i += 256) sp[i] = 0.0f;
    if (tid < 49)                 tl[tid]       = lf[(size_t)bc * 49 + tid];
    if (tid >= 64 && tid < 89)    tm[tid - 64]  = mf[(size_t)bc * 25 + (tid - 64)];
    if (tid >= 128 && tid < 137)  ts[tid - 128] = sf[(size_t)bc * 9  + (tid - 128)];
    __syncthreads();
    for (int i = tid; i < 841; i += 256) {
        int y = i / 29, x = i % 29;
        sp[(y + 2) * 33 + (x + 2)] = s[(size_t)bc * 841 + i];
    }
    __syncthreads();

    // lc: pad=2 -> s coord (y-2+dy, x-2+dx) == padded (y+dy, x+dx)
    for (int o = tid; o < 729; o += 256) {
        int y = o / 27, x = o % 27;
        float a = 0.0f;
        #pragma unroll
        for (int dy = 0; dy < 7; ++dy)
            #pragma unroll
            for (int dx = 0; dx < 7; ++dx)
                a = fmaf(tl[dy * 7 + dx], sp[(y + dy) * 33 + (x + dx)], a);
        lc[(size_t)bc * 729 + o] = a;
    }
    // mc: no pad -> padded index +2
    for (int o = tid; o < 625; o += 256) {
        int y = o / 25, x = o % 25;
        float a = 0.0f;
        #pragma unroll
        for (int dy = 0; dy < 5; ++dy)
            #pragma unroll
            for (int dx = 0; dx < 5; ++dx)
                a = fmaf(tm[dy * 5 + dx], sp[(y + dy + 2) * 33 + (x + dx + 2)], a);
        mc[(size_t)bc * 625 + o] = a;
    }
    // sc
    for (int o = tid; o < 729; o += 256) {
        int y = o / 27, x = o % 27;
        float a = 0.0f;
        #pragma unroll
        for (int dy = 0; dy < 3; ++dy)
            #pragma unroll
            for (int dx = 0; dx < 3; ++dx)
                a = fmaf(ts[dy * 3 + dx], sp[(y + dy + 2) * 33 + (x + dx + 2)], a);
        sc[(size_t)bc * 729 + o] = a;
    }
}

// ---------------------------------------------------------------------------
// Kernel C: fused score head.
// z = w2 . relu(BN(W1 . x + b1)) + b2 ; out = sigmoid(z)
// Block: 256 threads, tile = 256 couts x 32 pixels (K=256), per-thread 8x4.
// The 256-channel intermediate never hits global memory.
// grid = (ceil(Np/32), 64)
// ---------------------------------------------------------------------------
__global__ __launch_bounds__(256) void head_kernel(
    const float* __restrict__ X,      // (64,256,Np)
    const float* __restrict__ w1,     // (256,256)
    const float* __restrict__ b1,
    const float* __restrict__ g1, const float* __restrict__ be1,
    const float* __restrict__ m1, const float* __restrict__ v1,
    const float* __restrict__ w2,     // (256)
    const float* __restrict__ b2,     // (1)
    float* __restrict__ out,          // (64,Np)
    int Np)
{
    const int b  = blockIdx.y;
    const int p0 = blockIdx.x * 32;
    const int tid = threadIdx.x;
    const int pg = tid & 7;    // pixels pg*4 .. pg*4+3
    const int cg = tid >> 3;   // couts  cg*8 .. cg*8+7

    __shared__ __align__(16) float xsm[32 * 36];    // [k][pix]
    __shared__ __align__(16) float wsm[32 * 264];   // [k][cout]
    __shared__ float red[32 * 33];                  // [pix][cg]

    float acc[8][4];
    #pragma unroll
    for (int i = 0; i < 8; ++i)
        #pragma unroll
        for (int j = 0; j < 4; ++j) acc[i][j] = 0.0f;

    for (int k0 = 0; k0 < 256; k0 += 32) {
        for (int i = tid; i < 1024; i += 256) {
            int kk = i >> 5, pp = i & 31;
            int p = p0 + pp;
            xsm[kk * 36 + pp] = (p < Np) ? X[((size_t)(b * 256 + k0 + kk)) * Np + p] : 0.0f;
        }
        for (int i = tid; i < 8192; i += 256) {
            int co = i >> 5, kk = i & 31;
            wsm[kk * 264 + co] = w1[(size_t)co * 256 + k0 + kk];
        }
        __syncthreads();
        #pragma unroll 4
        for (int kk = 0; kk < 32; ++kk) {
            const float4 xv = *(const float4*)(xsm + kk * 36 + pg * 4);
            const float4 wa = *(const float4*)(wsm + kk * 264 + cg * 8);
            const float4 wb = *(const float4*)(wsm + kk * 264 + cg * 8 + 4);
            const float xr[4] = {xv.x, xv.y, xv.z, xv.w};
            const float wr[8] = {wa.x, wa.y, wa.z, wa.w, wb.x, wb.y, wb.z, wb.w};
            #pragma unroll
            for (int ii = 0; ii < 8; ++ii)
                #pragma unroll
                for (int jj = 0; jj < 4; ++jj)
                    acc[ii][jj] = fmaf(wr[ii], xr[jj], acc[ii][jj]);
        }
        __syncthreads();
    }

    float part[4] = {0.0f, 0.0f, 0.0f, 0.0f};
    #pragma unroll
    for (int ii = 0; ii < 8; ++ii) {
        const int co = cg * 8 + ii;
        const float A   = g1[co] * rsqrtf(v1[co] + 1e-5f);
        const float OFF = fmaf(b1[co] - m1[co], A, be1[co]);
        const float wc  = w2[co];
        #pragma unroll
        for (int jj = 0; jj < 4; ++jj) {
            float y = fmaxf(fmaf(acc[ii][jj], A, OFF), 0.0f);
            part[jj] = fmaf(wc, y, part[jj]);
        }
    }
    #pragma unroll
    for (int jj = 0; jj < 4; ++jj) red[(pg * 4 + jj) * 33 + cg] = part[jj];
    __syncthreads();
    if (tid < 32) {
        float z = b2[0];
        #pragma unroll 8
        for (int c = 0; c < 32; ++c) z += red[tid * 33 + c];
        if (p0 + tid < Np)
            out[(size_t)b * Np + p0 + tid] = 1.0f / (1.0f + expf(-z));
    }
}

// ---------------------------------------------------------------------------
extern "C" void kernel_launch(void* const* d_in, const int* in_sizes, int n_in,
                              void* d_out, int out_size, void* d_ws, size_t ws_size,
                              hipStream_t stream)
{
    const float* large  = (const float*)d_in[0];
    const float* medium = (const float*)d_in[1];
    const float* small  = (const float*)d_in[2];
    const float* search = (const float*)d_in[3];
    const float* wt  = (const float*)d_in[4];
    const float* bt  = (const float*)d_in[5];
    const float* gt  = (const float*)d_in[6];
    const float* bet = (const float*)d_in[7];
    const float* mt  = (const float*)d_in[8];
    const float* vt  = (const float*)d_in[9];
    const float* wsc = (const float*)d_in[10];
    const float* bs  = (const float*)d_in[11];
    const float* gs  = (const float*)d_in[12];
    const float* bes = (const float*)d_in[13];
    const float* ms  = (const float*)d_in[14];
    const float* vs  = (const float*)d_in[15];
    const float* w1  = (const float*)d_in[16];
    const float* b1  = (const float*)d_in[17];
    const float* g1  = (const float*)d_in[18];
    const float* be1 = (const float*)d_in[19];
    const float* m1  = (const float*)d_in[20];
    const float* v1  = (const float*)d_in[21];
    const float* w2  = (const float*)d_in[22];
    const float* b2  = (const float*)d_in[23];

    float* ws = (float*)d_ws;
    size_t off = 0;
    float* lf = ws + off; off += (size_t)64 * 256 * 49;    // 802,816
    float* mf = ws + off; off += (size_t)64 * 256 * 25;    // 409,600
    float* sf = ws + off; off += (size_t)64 * 256 * 9;     // 147,456
    float* sq = ws + off; off += (size_t)64 * 256 * 841;   // 13,778,944
    float* lc = ws + off; off += (size_t)64 * 256 * 729;   // 11,943,936
    float* mc = ws + off; off += (size_t)64 * 256 * 625;   // 10,240,000
    float* sc = ws + off; off += (size_t)64 * 256 * 729;   // total ~188 MB

    dim3 blk(256);
    // conv_target on 3 template scales + conv_search
    cbr3x3_kernel<<<dim3(1, 4, 64), blk, 0, stream>>>(large,  wt,  bt, gt, bet, mt, vt, lf, 9, 9);
    cbr3x3_kernel<<<dim3(1, 4, 64), blk, 0, stream>>>(medium, wt,  bt, gt, bet, mt, vt, mf, 7, 7);
    cbr3x3_kernel<<<dim3(1, 4, 64), blk, 0, stream>>>(small,  wt,  bt, gt, bet, mt, vt, sf, 5, 5);
    cbr3x3_kernel<<<dim3(14, 4, 64), blk, 0, stream>>>(search, wsc, bs, gs, bes, ms, vs, sq, 31, 31);

    // fused 3-scale depthwise correlation
    corr_kernel<<<dim3(256, 64), blk, 0, stream>>>(lf, mf, sf, sq, lc, mc, sc);

    // fused score heads -> d_out (f32), concatenated [lc-head | mc-head | sc-head]
    float* outp = (float*)d_out;
    head_kernel<<<dim3(23, 64), blk, 0, stream>>>(lc, w1, b1, g1, be1, m1, v1, w2, b2, outp, 729);
    head_kernel<<<dim3(20, 64), blk, 0, stream>>>(mc, w1, b1, g1, be1, m1, v1, w2, b2, outp + 46656, 625);
    head_kernel<<<dim3(23, 64), blk, 0, stream>>>(sc, w1, b1, g1, be1, m1, v1, w2, b2, outp + 86656, 729);
}

// Round 3
// 1186.544 us; speedup vs baseline: 2.3705x; 2.3705x over previous
//
#include <hip/hip_runtime.h>
#include <math.h>
#include <stdint.h>

typedef __attribute__((ext_vector_type(8))) short short8;
typedef __attribute__((ext_vector_type(4))) float floatx4;

// fp32 -> (bf16 hi | bf16 lo) packed u32.  hi = RNE(x), lo = RNE(x - hi).
__device__ __forceinline__ uint32_t pack_hilo(float x) {
    uint32_t u = __float_as_uint(x);
    uint32_t hi = (u + 0x7FFFu + ((u >> 16) & 1u)) & 0xFFFF0000u;
    float r = x - __uint_as_float(hi);
    uint32_t v = __float_as_uint(r);
    uint32_t lo = ((v + 0x7FFFu + ((v >> 16) & 1u)) >> 16) & 0xFFFFu;
    return hi | lo;
}

// ---------------------------------------------------------------------------
// Prep: x (64,256,HW) fp32 -> xh,xl (64,HW,256) bf16 shorts (ci contiguous).
// grid (ceil(HW/64), 4, 64), block 256
// ---------------------------------------------------------------------------
__global__ __launch_bounds__(256) void prep_x_split(
    const float* __restrict__ x, short* __restrict__ xh, short* __restrict__ xl,
    int HW)
{
    const int b = blockIdx.z, c0 = blockIdx.y * 64, p0 = blockIdx.x * 64;
    const int tid = threadIdx.x;
    const int a = tid & 63, g = tid >> 6;
    __shared__ uint32_t t[64][65];
    #pragma unroll
    for (int i = 0; i < 16; ++i) {
        int c = g + i * 4;
        int p = p0 + a;
        float v = (p < HW) ? x[((size_t)(b * 256) + c0 + c) * HW + p] : 0.0f;
        t[c][a] = pack_hilo(v);
    }
    __syncthreads();
    const int j = tid & 31;     // channel pair
    const int gg = tid >> 5;    // 0..7
    #pragma unroll
    for (int i = 0; i < 8; ++i) {
        int p = gg + i * 8;
        if (p0 + p < HW) {
            uint32_t w0 = t[2 * j][p], w1 = t[2 * j + 1][p];
            size_t o = ((size_t)b * HW + p0 + p) * 256 + c0 + 2 * j;
            *(uint32_t*)(xh + o) = (w0 >> 16) | (w1 & 0xFFFF0000u);
            *(uint32_t*)(xl + o) = (w0 & 0xFFFFu) | (w1 << 16);
        }
    }
}

// ---------------------------------------------------------------------------
// Prep: w (256,256,3,3) fp32 -> wh,wl (9,256co,256ci) bf16 shorts.
// grid (128), block 256
// ---------------------------------------------------------------------------
__global__ __launch_bounds__(256) void prep_w_split(
    const float* __restrict__ w, short* __restrict__ wh, short* __restrict__ wl)
{
    const int idx = blockIdx.x * 256 + threadIdx.x;   // [0,32768): co*128 + cipair
    const int co = idx >> 7, jp = idx & 127;
    const float* s0 = w + ((size_t)co * 256 + 2 * jp) * 9;
    #pragma unroll
    for (int r = 0; r < 9; ++r) {
        uint32_t q0 = pack_hilo(s0[r]);
        uint32_t q1 = pack_hilo(s0[9 + r]);
        size_t o = (size_t)r * 65536 + (size_t)co * 256 + 2 * jp;
        *(uint32_t*)(wh + o) = (q0 >> 16) | (q1 & 0xFFFF0000u);
        *(uint32_t*)(wl + o) = (q0 & 0xFFFFu) | (q1 << 16);
    }
}

// ---------------------------------------------------------------------------
// MFMA split-bf16 3x3 conv (valid) + bias + BN + ReLU.
// Block tile: 128 couts x 128 pixels, K = 9 taps x 256 ci (chunks of 32 ci).
// Staging is a pure vector copy (hi/lo pre-split by prep). LDS rows: 32
// shorts (64 B), unpadded -> 2-way bank alias on frag reads (free).
// grid (ceil(P/128), 2, 64), block 256
// ---------------------------------------------------------------------------
__global__ __launch_bounds__(256) void conv_mfma_kernel(
    const short* __restrict__ xh, const short* __restrict__ xl,  // (64,HW,256)
    const short* __restrict__ wh, const short* __restrict__ wl,  // (9,256,256)
    const float* __restrict__ bias,
    const float* __restrict__ gam, const float* __restrict__ bet,
    const float* __restrict__ mu,  const float* __restrict__ var,
    float* __restrict__ out,           // (64,256,P) fp32
    int H, int W)
{
    const int HW = H * W;
    const int Wo = W - 2, P = Wo * Wo;
    const int b   = blockIdx.z;
    const int co0 = blockIdx.y * 128;
    const int p0  = blockIdx.x * 128;
    const int tid  = threadIdx.x;
    const int wave = tid >> 6, lane = tid & 63;
    const int l15  = lane & 15, quad = lane >> 4;

    __shared__ __align__(16) short a_h[128 * 32], a_l[128 * 32];
    __shared__ __align__(16) short b_h[128 * 32], b_l[128 * 32];

    const int row  = tid >> 1;          // co for A, px_local for B
    const int half = tid & 1;           // which 16-ci half of the 32-chunk

    const int pxs = p0 + row;
    const int pc  = (pxs < P) ? pxs : 0;
    const int oy  = pc / Wo, ox = pc % Wo;
    const size_t xbase = ((size_t)b * HW + oy * W + ox) * 256;
    const size_t wbase = (size_t)(co0 + row) * 256;

    floatx4 acc[2][8];
    #pragma unroll
    for (int s = 0; s < 2; ++s)
        #pragma unroll
        for (int t = 0; t < 8; ++t) acc[s][t] = (floatx4){0.f, 0.f, 0.f, 0.f};

    const int aoff0 = (wave * 32 + l15) * 32 + quad * 8;
    const int aoff1 = aoff0 + 16 * 32;
    int boff[8];
    #pragma unroll
    for (int t = 0; t < 8; ++t) boff[t] = (t * 16 + l15) * 32 + quad * 8;

    const int dst = row * 32 + half * 16;   // short offset of this thread's slice

    for (int r = 0; r < 9; ++r) {
        const int ry = r / 3, rx = r % 3;
        const size_t xsrc = xbase + (size_t)(ry * W + rx) * 256;
        const size_t wsrc = (size_t)r * 65536 + wbase;
        for (int c4 = 0; c4 < 8; ++c4) {
            const int cio = c4 * 32 + half * 16;
            {
                const uint4* s_ah = (const uint4*)(wh + wsrc + cio);
                const uint4* s_al = (const uint4*)(wl + wsrc + cio);
                const uint4* s_bh = (const uint4*)(xh + xsrc + cio);
                const uint4* s_bl = (const uint4*)(xl + xsrc + cio);
                uint4 vah0 = s_ah[0], vah1 = s_ah[1];
                uint4 val0 = s_al[0], val1 = s_al[1];
                uint4 vbh0 = s_bh[0], vbh1 = s_bh[1];
                uint4 vbl0 = s_bl[0], vbl1 = s_bl[1];
                *(uint4*)(a_h + dst)     = vah0;
                *(uint4*)(a_h + dst + 8) = vah1;
                *(uint4*)(a_l + dst)     = val0;
                *(uint4*)(a_l + dst + 8) = val1;
                *(uint4*)(b_h + dst)     = vbh0;
                *(uint4*)(b_h + dst + 8) = vbh1;
                *(uint4*)(b_l + dst)     = vbl0;
                *(uint4*)(b_l + dst + 8) = vbl1;
            }
            __syncthreads();
            short8 a0h = *(const short8*)(a_h + aoff0);
            short8 a0l = *(const short8*)(a_l + aoff0);
            short8 a1h = *(const short8*)(a_h + aoff1);
            short8 a1l = *(const short8*)(a_l + aoff1);
            #pragma unroll
            for (int t = 0; t < 8; ++t) {
                short8 vh = *(const short8*)(b_h + boff[t]);
                short8 vl = *(const short8*)(b_l + boff[t]);
                acc[0][t] = __builtin_amdgcn_mfma_f32_16x16x32_bf16(a0h, vh, acc[0][t], 0, 0, 0);
                acc[1][t] = __builtin_amdgcn_mfma_f32_16x16x32_bf16(a1h, vh, acc[1][t], 0, 0, 0);
                acc[0][t] = __builtin_amdgcn_mfma_f32_16x16x32_bf16(a0h, vl, acc[0][t], 0, 0, 0);
                acc[1][t] = __builtin_amdgcn_mfma_f32_16x16x32_bf16(a1h, vl, acc[1][t], 0, 0, 0);
                acc[0][t] = __builtin_amdgcn_mfma_f32_16x16x32_bf16(a0l, vh, acc[0][t], 0, 0, 0);
                acc[1][t] = __builtin_amdgcn_mfma_f32_16x16x32_bf16(a1l, vh, acc[1][t], 0, 0, 0);
            }
            __syncthreads();
        }
    }

    // epilogue: D layout col(px)=lane&15, row(co)=quad*4+reg  [verified m89/m91]
    #pragma unroll
    for (int s = 0; s < 2; ++s) {
        const int cobase = co0 + wave * 32 + s * 16 + quad * 4;
        #pragma unroll
        for (int reg = 0; reg < 4; ++reg) {
            const int co = cobase + reg;
            const float A   = gam[co] * rsqrtf(var[co] + 1e-5f);
            const float OFF = fmaf(bias[co] - mu[co], A, bet[co]);
            float* orow = out + ((size_t)(b * 256 + co)) * P;
            #pragma unroll
            for (int t = 0; t < 8; ++t) {
                int px = p0 + t * 16 + l15;
                if (px < P)
                    orow[px] = fmaxf(fmaf(acc[s][t][reg], A, OFF), 0.0f);
            }
        }
    }
}

// ---------------------------------------------------------------------------
// Kernel B: fused 3-scale depthwise cross-correlation (R1-proven).
// ---------------------------------------------------------------------------
__global__ __launch_bounds__(256) void corr_kernel(
    const float* __restrict__ lf, const float* __restrict__ mf,
    const float* __restrict__ sf, const float* __restrict__ s,
    float* __restrict__ lc, float* __restrict__ mc, float* __restrict__ sc)
{
    const int c = blockIdx.x, b = blockIdx.y;
    const int bc = b * 256 + c;
    const int tid = threadIdx.x;
    __shared__ float sp[33 * 33];
    __shared__ float tl[49], tm[25], ts[9];

    for (int i = tid; i < 33 * 33; i += 256) sp[i] = 0.0f;
    if (tid < 49)                 tl[tid]       = lf[(size_t)bc * 49 + tid];
    if (tid >= 64 && tid < 89)    tm[tid - 64]  = mf[(size_t)bc * 25 + (tid - 64)];
    if (tid >= 128 && tid < 137)  ts[tid - 128] = sf[(size_t)bc * 9  + (tid - 128)];
    __syncthreads();
    for (int i = tid; i < 841; i += 256) {
        int y = i / 29, x = i % 29;
        sp[(y + 2) * 33 + (x + 2)] = s[(size_t)bc * 841 + i];
    }
    __syncthreads();

    for (int o = tid; o < 729; o += 256) {
        int y = o / 27, x = o % 27;
        float a = 0.0f;
        #pragma unroll
        for (int dy = 0; dy < 7; ++dy)
            #pragma unroll
            for (int dx = 0; dx < 7; ++dx)
                a = fmaf(tl[dy * 7 + dx], sp[(y + dy) * 33 + (x + dx)], a);
        lc[(size_t)bc * 729 + o] = a;
    }
    for (int o = tid; o < 625; o += 256) {
        int y = o / 25, x = o % 25;
        float a = 0.0f;
        #pragma unroll
        for (int dy = 0; dy < 5; ++dy)
            #pragma unroll
            for (int dx = 0; dx < 5; ++dx)
                a = fmaf(tm[dy * 5 + dx], sp[(y + dy + 2) * 33 + (x + dx + 2)], a);
        mc[(size_t)bc * 625 + o] = a;
    }
    for (int o = tid; o < 729; o += 256) {
        int y = o / 27, x = o % 27;
        float a = 0.0f;
        #pragma unroll
        for (int dy = 0; dy < 3; ++dy)
            #pragma unroll
            for (int dx = 0; dx < 3; ++dx)
                a = fmaf(ts[dy * 3 + dx], sp[(y + dy + 2) * 33 + (x + dx + 2)], a);
        sc[(size_t)bc * 729 + o] = a;
    }
}

// ---------------------------------------------------------------------------
// Kernel C: fused score head (R1-proven).
// ---------------------------------------------------------------------------
__global__ __launch_bounds__(256) void head_kernel(
    const float* __restrict__ X,
    const float* __restrict__ w1,
    const float* __restrict__ b1,
    const float* __restrict__ g1, const float* __restrict__ be1,
    const float* __restrict__ m1, const float* __restrict__ v1,
    const float* __restrict__ w2,
    const float* __restrict__ b2,
    float* __restrict__ out,
    int Np)
{
    const int b  = blockIdx.y;
    const int p0 = blockIdx.x * 32;
    const int tid = threadIdx.x;
    const int pg = tid & 7;
    const int cg = tid >> 3;

    __shared__ __align__(16) float xsm[32 * 36];
    __shared__ __align__(16) float wsm[32 * 264];
    __shared__ float red[32 * 33];

    float acc[8][4];
    #pragma unroll
    for (int i = 0; i < 8; ++i)
        #pragma unroll
        for (int j = 0; j < 4; ++j) acc[i][j] = 0.0f;

    for (int k0 = 0; k0 < 256; k0 += 32) {
        for (int i = tid; i < 1024; i += 256) {
            int kk = i >> 5, pp = i & 31;
            int p = p0 + pp;
            xsm[kk * 36 + pp] = (p < Np) ? X[((size_t)(b * 256 + k0 + kk)) * Np + p] : 0.0f;
        }
        for (int i = tid; i < 8192; i += 256) {
            int co = i >> 5, kk = i & 31;
            wsm[kk * 264 + co] = w1[(size_t)co * 256 + k0 + kk];
        }
        __syncthreads();
        #pragma unroll 4
        for (int kk = 0; kk < 32; ++kk) {
            const float4 xv = *(const float4*)(xsm + kk * 36 + pg * 4);
            const float4 wa = *(const float4*)(wsm + kk * 264 + cg * 8);
            const float4 wb = *(const float4*)(wsm + kk * 264 + cg * 8 + 4);
            const float xr[4] = {xv.x, xv.y, xv.z, xv.w};
            const float wr[8] = {wa.x, wa.y, wa.z, wa.w, wb.x, wb.y, wb.z, wb.w};
            #pragma unroll
            for (int ii = 0; ii < 8; ++ii)
                #pragma unroll
                for (int jj = 0; jj < 4; ++jj)
                    acc[ii][jj] = fmaf(wr[ii], xr[jj], acc[ii][jj]);
        }
        __syncthreads();
    }

    float part[4] = {0.0f, 0.0f, 0.0f, 0.0f};
    #pragma unroll
    for (int ii = 0; ii < 8; ++ii) {
        const int co = cg * 8 + ii;
        const float A   = g1[co] * rsqrtf(v1[co] + 1e-5f);
        const float OFF = fmaf(b1[co] - m1[co], A, be1[co]);
        const float wc  = w2[co];
        #pragma unroll
        for (int jj = 0; jj < 4; ++jj) {
            float y = fmaxf(fmaf(acc[ii][jj], A, OFF), 0.0f);
            part[jj] = fmaf(wc, y, part[jj]);
        }
    }
    #pragma unroll
    for (int jj = 0; jj < 4; ++jj) red[(pg * 4 + jj) * 33 + cg] = part[jj];
    __syncthreads();
    if (tid < 32) {
        float z = b2[0];
        #pragma unroll 8
        for (int c = 0; c < 32; ++c) z += red[tid * 33 + c];
        if (p0 + tid < Np)
            out[(size_t)b * Np + p0 + tid] = 1.0f / (1.0f + expf(-z));
    }
}

// ---------------------------------------------------------------------------
extern "C" void kernel_launch(void* const* d_in, const int* in_sizes, int n_in,
                              void* d_out, int out_size, void* d_ws, size_t ws_size,
                              hipStream_t stream)
{
    const float* large  = (const float*)d_in[0];
    const float* medium = (const float*)d_in[1];
    const float* small  = (const float*)d_in[2];
    const float* search = (const float*)d_in[3];
    const float* wt  = (const float*)d_in[4];
    const float* bt  = (const float*)d_in[5];
    const float* gt  = (const float*)d_in[6];
    const float* bet = (const float*)d_in[7];
    const float* mt  = (const float*)d_in[8];
    const float* vt  = (const float*)d_in[9];
    const float* wsc = (const float*)d_in[10];
    const float* bs  = (const float*)d_in[11];
    const float* gs  = (const float*)d_in[12];
    const float* bes = (const float*)d_in[13];
    const float* ms  = (const float*)d_in[14];
    const float* vs  = (const float*)d_in[15];
    const float* w1  = (const float*)d_in[16];
    const float* b1  = (const float*)d_in[17];
    const float* g1  = (const float*)d_in[18];
    const float* be1 = (const float*)d_in[19];
    const float* m1  = (const float*)d_in[20];
    const float* v1  = (const float*)d_in[21];
    const float* w2  = (const float*)d_in[22];
    const float* b2  = (const float*)d_in[23];

    float* ws = (float*)d_ws;
    size_t off = 0;
    float* lf = ws + off; off += (size_t)64 * 256 * 49;
    float* mf = ws + off; off += (size_t)64 * 256 * 25;
    float* sf = ws + off; off += (size_t)64 * 256 * 9;
    float* sq = ws + off; off += (size_t)64 * 256 * 841;
    float* lc = ws + off; off += (size_t)64 * 256 * 729;
    float* mc = ws + off; off += (size_t)64 * 256 * 625;
    float* sc = ws + off; off += (size_t)64 * 256 * 729;   // ~197 MB total

    // Aliased prep buffers (dead before lc/mc/sc are produced by corr):
    // search hi/lo over lc(+into mc):
    short* xh_s = (short*)lc;                                  // 15,745,024 shorts
    short* xl_s = (short*)lc + 15745024;                       // ends at 31,490,048 shorts
                                                               //   = 15,745,024 floats <= lc+mc (22,183,936 floats)
    // templates + weights over sc (23,887,872 shorts available):
    short* base = (short*)sc;
    short* xh_L = base;                 // 1,327,104
    short* xl_L = base + 1327104;       // 1,327,104
    short* xh_M = base + 2654208;       //   802,816
    short* xl_M = base + 3457024;       //   802,816
    short* xh_S = base + 4259840;       //   409,600
    short* xl_S = base + 4669440;       //   409,600
    short* wh_t = base + 5079040;       //   589,824
    short* wl_t = base + 5668864;       //   589,824
    short* wh_s = base + 6258688;       //   589,824
    short* wl_s = base + 6848512;       //   589,824  -> ends 7,438,336 < 23,887,872

    dim3 blk(256);
    // pack weights + activations into pre-split bf16 hi/lo
    prep_w_split<<<dim3(128), blk, 0, stream>>>(wt,  wh_t, wl_t);
    prep_w_split<<<dim3(128), blk, 0, stream>>>(wsc, wh_s, wl_s);
    prep_x_split<<<dim3(16, 4, 64), blk, 0, stream>>>(search, xh_s, xl_s, 961);
    prep_x_split<<<dim3(2, 4, 64),  blk, 0, stream>>>(large,  xh_L, xl_L, 81);
    prep_x_split<<<dim3(1, 4, 64),  blk, 0, stream>>>(medium, xh_M, xl_M, 49);
    prep_x_split<<<dim3(1, 4, 64),  blk, 0, stream>>>(small,  xh_S, xl_S, 25);

    // MFMA convs (+bias+BN+ReLU)
    conv_mfma_kernel<<<dim3(1, 2, 64), blk, 0, stream>>>(xh_L, xl_L, wh_t, wl_t, bt, gt, bet, mt, vt, lf, 9, 9);
    conv_mfma_kernel<<<dim3(1, 2, 64), blk, 0, stream>>>(xh_M, xl_M, wh_t, wl_t, bt, gt, bet, mt, vt, mf, 7, 7);
    conv_mfma_kernel<<<dim3(1, 2, 64), blk, 0, stream>>>(xh_S, xl_S, wh_t, wl_t, bt, gt, bet, mt, vt, sf, 5, 5);
    conv_mfma_kernel<<<dim3(7, 2, 64), blk, 0, stream>>>(xh_s, xl_s, wh_s, wl_s, bs, gs, bes, ms, vs, sq, 31, 31);

    // fused 3-scale depthwise correlation (overwrites the aliased prep bufs)
    corr_kernel<<<dim3(256, 64), blk, 0, stream>>>(lf, mf, sf, sq, lc, mc, sc);

    // fused score heads -> d_out
    float* outp = (float*)d_out;
    head_kernel<<<dim3(23, 64), blk, 0, stream>>>(lc, w1, b1, g1, be1, m1, v1, w2, b2, outp, 729);
    head_kernel<<<dim3(20, 64), blk, 0, stream>>>(mc, w1, b1, g1, be1, m1, v1, w2, b2, outp + 46656, 625);
    head_kernel<<<dim3(23, 64), blk, 0, stream>>>(sc, w1, b1, g1, be1, m1, v1, w2, b2, outp + 86656, 729);
}

// Round 4
// 1135.781 us; speedup vs baseline: 2.4764x; 1.0447x over previous
//
#include <hip/hip_runtime.h>
#include <math.h>
#include <stdint.h>

typedef __attribute__((ext_vector_type(8))) short short8;
typedef __attribute__((ext_vector_type(4))) float floatx4;

// fp32 -> (bf16 hi | bf16 lo) packed u32.  hi = RNE(x), lo = RNE(x - hi).
__device__ __forceinline__ uint32_t pack_hilo(float x) {
    uint32_t u = __float_as_uint(x);
    uint32_t hi = (u + 0x7FFFu + ((u >> 16) & 1u)) & 0xFFFF0000u;
    float r = x - __uint_as_float(hi);
    uint32_t v = __float_as_uint(r);
    uint32_t lo = ((v + 0x7FFFu + ((v >> 16) & 1u)) >> 16) & 0xFFFFu;
    return hi | lo;
}

// ---------------------------------------------------------------------------
// Prep: x (64,256,HW) fp32 -> xh,xl (64,HW,256) bf16 shorts (ci contiguous).
// ---------------------------------------------------------------------------
__global__ __launch_bounds__(256) void prep_x_split(
    const float* __restrict__ x, short* __restrict__ xh, short* __restrict__ xl,
    int HW)
{
    const int b = blockIdx.z, c0 = blockIdx.y * 64, p0 = blockIdx.x * 64;
    const int tid = threadIdx.x;
    const int a = tid & 63, g = tid >> 6;
    __shared__ uint32_t t[64][65];
    #pragma unroll
    for (int i = 0; i < 16; ++i) {
        int c = g + i * 4;
        int p = p0 + a;
        float v = (p < HW) ? x[((size_t)(b * 256) + c0 + c) * HW + p] : 0.0f;
        t[c][a] = pack_hilo(v);
    }
    __syncthreads();
    const int j = tid & 31;
    const int gg = tid >> 5;
    #pragma unroll
    for (int i = 0; i < 8; ++i) {
        int p = gg + i * 8;
        if (p0 + p < HW) {
            uint32_t w0 = t[2 * j][p], w1 = t[2 * j + 1][p];
            size_t o = ((size_t)b * HW + p0 + p) * 256 + c0 + 2 * j;
            *(uint32_t*)(xh + o) = (w0 >> 16) | (w1 & 0xFFFF0000u);
            *(uint32_t*)(xl + o) = (w0 & 0xFFFFu) | (w1 << 16);
        }
    }
}

// ---------------------------------------------------------------------------
// Prep: w (256,256,3,3) fp32 -> wh,wl (9,256co,256ci) bf16 shorts.
// ---------------------------------------------------------------------------
__global__ __launch_bounds__(256) void prep_w_split(
    const float* __restrict__ w, short* __restrict__ wh, short* __restrict__ wl)
{
    const int idx = blockIdx.x * 256 + threadIdx.x;
    const int co = idx >> 7, jp = idx & 127;
    const float* s0 = w + ((size_t)co * 256 + 2 * jp) * 9;
    #pragma unroll
    for (int r = 0; r < 9; ++r) {
        uint32_t q0 = pack_hilo(s0[r]);
        uint32_t q1 = pack_hilo(s0[9 + r]);
        size_t o = (size_t)r * 65536 + (size_t)co * 256 + 2 * jp;
        *(uint32_t*)(wh + o) = (q0 >> 16) | (q1 & 0xFFFF0000u);
        *(uint32_t*)(wl + o) = (q0 & 0xFFFFu) | (q1 << 16);
    }
}

// ---------------------------------------------------------------------------
// MFMA split-bf16 3x3 conv (valid) + bias + BN + ReLU (R3-proven).
// ---------------------------------------------------------------------------
__global__ __launch_bounds__(256) void conv_mfma_kernel(
    const short* __restrict__ xh, const short* __restrict__ xl,
    const short* __restrict__ wh, const short* __restrict__ wl,
    const float* __restrict__ bias,
    const float* __restrict__ gam, const float* __restrict__ bet,
    const float* __restrict__ mu,  const float* __restrict__ var,
    float* __restrict__ out, int H, int W)
{
    const int HW = H * W;
    const int Wo = W - 2, P = Wo * Wo;
    const int b   = blockIdx.z;
    const int co0 = blockIdx.y * 128;
    const int p0  = blockIdx.x * 128;
    const int tid  = threadIdx.x;
    const int wave = tid >> 6, lane = tid & 63;
    const int l15  = lane & 15, quad = lane >> 4;

    __shared__ __align__(16) short a_h[128 * 32], a_l[128 * 32];
    __shared__ __align__(16) short b_h[128 * 32], b_l[128 * 32];

    const int row  = tid >> 1;
    const int half = tid & 1;

    const int pxs = p0 + row;
    const int pc  = (pxs < P) ? pxs : 0;
    const int oy  = pc / Wo, ox = pc % Wo;
    const size_t xbase = ((size_t)b * HW + oy * W + ox) * 256;
    const size_t wbase = (size_t)(co0 + row) * 256;

    floatx4 acc[2][8];
    #pragma unroll
    for (int s = 0; s < 2; ++s)
        #pragma unroll
        for (int t = 0; t < 8; ++t) acc[s][t] = (floatx4){0.f, 0.f, 0.f, 0.f};

    const int aoff0 = (wave * 32 + l15) * 32 + quad * 8;
    const int aoff1 = aoff0 + 16 * 32;
    int boff[8];
    #pragma unroll
    for (int t = 0; t < 8; ++t) boff[t] = (t * 16 + l15) * 32 + quad * 8;

    const int dst = row * 32 + half * 16;

    for (int r = 0; r < 9; ++r) {
        const int ry = r / 3, rx = r % 3;
        const size_t xsrc = xbase + (size_t)(ry * W + rx) * 256;
        const size_t wsrc = (size_t)r * 65536 + wbase;
        for (int c4 = 0; c4 < 8; ++c4) {
            const int cio = c4 * 32 + half * 16;
            {
                const uint4* s_ah = (const uint4*)(wh + wsrc + cio);
                const uint4* s_al = (const uint4*)(wl + wsrc + cio);
                const uint4* s_bh = (const uint4*)(xh + xsrc + cio);
                const uint4* s_bl = (const uint4*)(xl + xsrc + cio);
                uint4 vah0 = s_ah[0], vah1 = s_ah[1];
                uint4 val0 = s_al[0], val1 = s_al[1];
                uint4 vbh0 = s_bh[0], vbh1 = s_bh[1];
                uint4 vbl0 = s_bl[0], vbl1 = s_bl[1];
                *(uint4*)(a_h + dst)     = vah0;
                *(uint4*)(a_h + dst + 8) = vah1;
                *(uint4*)(a_l + dst)     = val0;
                *(uint4*)(a_l + dst + 8) = val1;
                *(uint4*)(b_h + dst)     = vbh0;
                *(uint4*)(b_h + dst + 8) = vbh1;
                *(uint4*)(b_l + dst)     = vbl0;
                *(uint4*)(b_l + dst + 8) = vbl1;
            }
            __syncthreads();
            short8 a0h = *(const short8*)(a_h + aoff0);
            short8 a0l = *(const short8*)(a_l + aoff0);
            short8 a1h = *(const short8*)(a_h + aoff1);
            short8 a1l = *(const short8*)(a_l + aoff1);
            #pragma unroll
            for (int t = 0; t < 8; ++t) {
                short8 vh = *(const short8*)(b_h + boff[t]);
                short8 vl = *(const short8*)(b_l + boff[t]);
                acc[0][t] = __builtin_amdgcn_mfma_f32_16x16x32_bf16(a0h, vh, acc[0][t], 0, 0, 0);
                acc[1][t] = __builtin_amdgcn_mfma_f32_16x16x32_bf16(a1h, vh, acc[1][t], 0, 0, 0);
                acc[0][t] = __builtin_amdgcn_mfma_f32_16x16x32_bf16(a0h, vl, acc[0][t], 0, 0, 0);
                acc[1][t] = __builtin_amdgcn_mfma_f32_16x16x32_bf16(a1h, vl, acc[1][t], 0, 0, 0);
                acc[0][t] = __builtin_amdgcn_mfma_f32_16x16x32_bf16(a0l, vh, acc[0][t], 0, 0, 0);
                acc[1][t] = __builtin_amdgcn_mfma_f32_16x16x32_bf16(a1l, vh, acc[1][t], 0, 0, 0);
            }
            __syncthreads();
        }
    }

    #pragma unroll
    for (int s = 0; s < 2; ++s) {
        const int cobase = co0 + wave * 32 + s * 16 + quad * 4;
        #pragma unroll
        for (int reg = 0; reg < 4; ++reg) {
            const int co = cobase + reg;
            const float A   = gam[co] * rsqrtf(var[co] + 1e-5f);
            const float OFF = fmaf(bias[co] - mu[co], A, bet[co]);
            float* orow = out + ((size_t)(b * 256 + co)) * P;
            #pragma unroll
            for (int t = 0; t < 8; ++t) {
                int px = p0 + t * 16 + l15;
                if (px < P)
                    orow[px] = fmaxf(fmaf(acc[s][t][reg], A, OFF), 0.0f);
            }
        }
    }
}

// ---------------------------------------------------------------------------
// corr v2: one wave per (b,c); templates in VGPRs; 4-wide outputs with
// b128 sliding-window reads from a padded 33x36 LDS plane.
// grid (64, 64): blockIdx.x = channel group (4 ch), blockIdx.y = b.
// ---------------------------------------------------------------------------
__global__ __launch_bounds__(256) void corr_kernel(
    const float* __restrict__ lf, const float* __restrict__ mf,
    const float* __restrict__ sf, const float* __restrict__ s,
    float* __restrict__ lc, float* __restrict__ mc, float* __restrict__ sc)
{
    const int b = blockIdx.y;
    const int wave = threadIdx.x >> 6, lane = threadIdx.x & 63;
    const int c = blockIdx.x * 4 + wave;
    const int bc = b * 256 + c;

    __shared__ __align__(16) float sp[4][33 * 36];
    __shared__ float tw[4][96];

    float* P = sp[wave];
    for (int i = lane; i < 33 * 36; i += 64) P[i] = 0.0f;
    if (lane < 49) tw[wave][lane]      = lf[(size_t)bc * 49 + lane];
    if (lane < 25) tw[wave][49 + lane] = mf[(size_t)bc * 25 + lane];
    if (lane < 9)  tw[wave][74 + lane] = sf[(size_t)bc * 9 + lane];
    for (int i = lane; i < 841; i += 64) {
        int y = i / 29, x = i - y * 29;
        P[(y + 2) * 36 + (x + 2)] = s[(size_t)bc * 841 + i];
    }
    __syncthreads();

    // ---- lc: 7x7 template, pad 2 -> 27x27 ----
    {
        float t7[49];
        #pragma unroll
        for (int k = 0; k < 49; ++k) t7[k] = tw[wave][k];
        #pragma unroll
        for (int it = 0; it < 3; ++it) {
            int og = lane + it * 64;
            bool v = (og < 189);
            int y = v ? (og / 7) : 0;
            int xg = og - (og / 7) * 7;
            int x0 = xg * 4;
            float a0 = 0, a1 = 0, a2 = 0, a3 = 0;
            #pragma unroll
            for (int dy = 0; dy < 7; ++dy) {
                const float* rp = P + (y + dy) * 36 + x0;
                float4 fA = *(const float4*)rp;
                float4 fB = *(const float4*)(rp + 4);
                float4 fC = *(const float4*)(rp + 8);
                float f[12] = {fA.x, fA.y, fA.z, fA.w, fB.x, fB.y, fB.z, fB.w,
                               fC.x, fC.y, fC.z, fC.w};
                #pragma unroll
                for (int dx = 0; dx < 7; ++dx) {
                    float t = t7[dy * 7 + dx];
                    a0 = fmaf(t, f[dx], a0);
                    a1 = fmaf(t, f[dx + 1], a1);
                    a2 = fmaf(t, f[dx + 2], a2);
                    a3 = fmaf(t, f[dx + 3], a3);
                }
            }
            if (v) {
                size_t o = (size_t)bc * 729 + y * 27 + x0;
                lc[o] = a0;
                lc[o + 1] = a1;
                lc[o + 2] = a2;
                if (x0 + 3 < 27) lc[o + 3] = a3;
            }
        }
    }
    // ---- mc: 5x5, no pad -> 25x25 (window offset +2 in padded plane) ----
    {
        float t5[25];
        #pragma unroll
        for (int k = 0; k < 25; ++k) t5[k] = tw[wave][49 + k];
        #pragma unroll
        for (int it = 0; it < 3; ++it) {
            int og = lane + it * 64;
            bool v = (og < 175);
            int y = v ? (og / 7) : 0;
            int xg = og - (og / 7) * 7;
            int x0 = xg * 4;
            float a0 = 0, a1 = 0, a2 = 0, a3 = 0;
            #pragma unroll
            for (int dy = 0; dy < 5; ++dy) {
                const float* rp = P + (y + 2 + dy) * 36 + x0;
                float4 fA = *(const float4*)rp;
                float4 fB = *(const float4*)(rp + 4);
                float4 fC = *(const float4*)(rp + 8);
                float f[12] = {fA.x, fA.y, fA.z, fA.w, fB.x, fB.y, fB.z, fB.w,
                               fC.x, fC.y, fC.z, fC.w};
                #pragma unroll
                for (int dx = 0; dx < 5; ++dx) {
                    float t = t5[dy * 5 + dx];
                    a0 = fmaf(t, f[2 + dx], a0);
                    a1 = fmaf(t, f[3 + dx], a1);
                    a2 = fmaf(t, f[4 + dx], a2);
                    a3 = fmaf(t, f[5 + dx], a3);
                }
            }
            if (v) {
                size_t o = (size_t)bc * 625 + y * 25 + x0;
                mc[o] = a0;
                if (x0 + 1 < 25) mc[o + 1] = a1;
                if (x0 + 2 < 25) mc[o + 2] = a2;
                if (x0 + 3 < 25) mc[o + 3] = a3;
            }
        }
    }
    // ---- sc: 3x3, no pad -> 27x27 ----
    {
        float t3[9];
        #pragma unroll
        for (int k = 0; k < 9; ++k) t3[k] = tw[wave][74 + k];
        #pragma unroll
        for (int it = 0; it < 3; ++it) {
            int og = lane + it * 64;
            bool v = (og < 189);
            int y = v ? (og / 7) : 0;
            int xg = og - (og / 7) * 7;
            int x0 = xg * 4;
            float a0 = 0, a1 = 0, a2 = 0, a3 = 0;
            #pragma unroll
            for (int dy = 0; dy < 3; ++dy) {
                const float* rp = P + (y + 2 + dy) * 36 + x0;
                float4 fA = *(const float4*)rp;
                float4 fB = *(const float4*)(rp + 4);
                float f[8] = {fA.x, fA.y, fA.z, fA.w, fB.x, fB.y, fB.z, fB.w};
                #pragma unroll
                for (int dx = 0; dx < 3; ++dx) {
                    float t = t3[dy * 3 + dx];
                    a0 = fmaf(t, f[2 + dx], a0);
                    a1 = fmaf(t, f[3 + dx], a1);
                    a2 = fmaf(t, f[4 + dx], a2);
                    a3 = fmaf(t, f[5 + dx], a3);
                }
            }
            if (v) {
                size_t o = (size_t)bc * 729 + y * 27 + x0;
                sc[o] = a0;
                sc[o + 1] = a1;
                sc[o + 2] = a2;
                if (x0 + 3 < 27) sc[o + 3] = a3;
            }
        }
    }
}

// ---------------------------------------------------------------------------
// head v2 (MFMA): sigmoid(w2 . relu(BN(W1.x+b1)) + b2), split-bf16 3-term.
// Block: 256 co x 128 px, K=256 in 8 chunks; w1 and X hi/lo-packed inline.
// grid (ceil(Np/128), 64)
// ---------------------------------------------------------------------------
__global__ __launch_bounds__(256) void head_mfma_kernel(
    const float* __restrict__ X,      // (64,256,Np) fp32
    const float* __restrict__ w1,     // (256,256)
    const float* __restrict__ b1,
    const float* __restrict__ g1, const float* __restrict__ be1,
    const float* __restrict__ m1, const float* __restrict__ v1,
    const float* __restrict__ w2, const float* __restrict__ b2,
    float* __restrict__ out,          // (64,Np)
    int Np)
{
    const int b  = blockIdx.y;
    const int p0 = blockIdx.x * 128;
    const int tid = threadIdx.x;
    const int wave = tid >> 6, lane = tid & 63;
    const int l15 = lane & 15, quad = lane >> 4;

    __shared__ __align__(16) short Ah[256 * 32], Al[256 * 32];  // [co][ci], stride 32
    __shared__ __align__(16) short Bh[128 * 40], Bl[128 * 40];  // [px][ci], stride 40
    __shared__ float red[128 * 17];

    floatx4 acc[4][8];
    #pragma unroll
    for (int m = 0; m < 4; ++m)
        #pragma unroll
        for (int n = 0; n < 8; ++n) acc[m][n] = (floatx4){0.f, 0.f, 0.f, 0.f};

    const int cp  = tid & 15;    // ci pair for B staging
    const int pxq = tid >> 4;    // px quad (16 quads = 64 px), x2 halves

    for (int k0 = 0; k0 < 256; k0 += 32) {
        // ---- stage A: thread = co row, pack w1[co][k0..k0+31] ----
        {
            const float* src = w1 + (size_t)tid * 256 + k0;
            uint32_t h[16], l[16];
            #pragma unroll
            for (int q = 0; q < 8; ++q) {
                float4 v4 = *(const float4*)(src + q * 4);
                uint32_t pa = pack_hilo(v4.x), pb = pack_hilo(v4.y);
                uint32_t pc = pack_hilo(v4.z), pd = pack_hilo(v4.w);
                h[q * 2]     = (pa >> 16) | (pb & 0xFFFF0000u);
                h[q * 2 + 1] = (pc >> 16) | (pd & 0xFFFF0000u);
                l[q * 2]     = (pa & 0xFFFFu) | (pb << 16);
                l[q * 2 + 1] = (pc & 0xFFFFu) | (pd << 16);
            }
            #pragma unroll
            for (int q = 0; q < 4; ++q) {
                uint4 uh; uh.x = h[q*4]; uh.y = h[q*4+1]; uh.z = h[q*4+2]; uh.w = h[q*4+3];
                uint4 ul; ul.x = l[q*4]; ul.y = l[q*4+1]; ul.z = l[q*4+2]; ul.w = l[q*4+3];
                *(uint4*)(Ah + tid * 32 + q * 8) = uh;
                *(uint4*)(Al + tid * 32 + q * 8) = ul;
            }
        }
        // ---- stage B: pack X[ci pair][4 px] -> [px][ci] ----
        #pragma unroll
        for (int halfp = 0; halfp < 2; ++halfp) {
            int pxl = halfp * 64 + pxq * 4;
            int gp = p0 + pxl;
            const float* r0 = X + ((size_t)(b * 256) + k0 + 2 * cp) * Np + gp;
            const float* r1 = r0 + Np;
            #pragma unroll
            for (int j = 0; j < 4; ++j) {
                float u = (gp + j < Np) ? r0[j] : 0.0f;
                float v = (gp + j < Np) ? r1[j] : 0.0f;
                uint32_t hu = pack_hilo(u), hv = pack_hilo(v);
                int o = (pxl + j) * 40 + 2 * cp;
                *(uint32_t*)(Bh + o) = (hu >> 16) | (hv & 0xFFFF0000u);
                *(uint32_t*)(Bl + o) = (hu & 0xFFFFu) | (hv << 16);
            }
        }
        __syncthreads();
        // ---- MFMA: wave covers co [64*wave, 64*wave+64) x 128 px ----
        short8 amh[4], aml[4];
        #pragma unroll
        for (int m = 0; m < 4; ++m) {
            int ao = (wave * 64 + m * 16 + l15) * 32 + quad * 8;
            amh[m] = *(const short8*)(Ah + ao);
            aml[m] = *(const short8*)(Al + ao);
        }
        #pragma unroll
        for (int n = 0; n < 8; ++n) {
            int bo = (n * 16 + l15) * 40 + quad * 8;
            short8 bh = *(const short8*)(Bh + bo);
            short8 bl = *(const short8*)(Bl + bo);
            #pragma unroll
            for (int m = 0; m < 4; ++m) {
                acc[m][n] = __builtin_amdgcn_mfma_f32_16x16x32_bf16(amh[m], bh, acc[m][n], 0, 0, 0);
                acc[m][n] = __builtin_amdgcn_mfma_f32_16x16x32_bf16(amh[m], bl, acc[m][n], 0, 0, 0);
                acc[m][n] = __builtin_amdgcn_mfma_f32_16x16x32_bf16(aml[m], bh, acc[m][n], 0, 0, 0);
            }
        }
        __syncthreads();
    }

    // ---- epilogue: per-lane partial over its 16 co, then cross-wave reduce ----
    float Ac[16], Oc[16], Wc[16];
    #pragma unroll
    for (int m = 0; m < 4; ++m)
        #pragma unroll
        for (int reg = 0; reg < 4; ++reg) {
            int co = wave * 64 + m * 16 + quad * 4 + reg;
            float A = g1[co] * rsqrtf(v1[co] + 1e-5f);
            Ac[m * 4 + reg] = A;
            Oc[m * 4 + reg] = fmaf(b1[co] - m1[co], A, be1[co]);
            Wc[m * 4 + reg] = w2[co];
        }
    #pragma unroll
    for (int n = 0; n < 8; ++n) {
        float part = 0.0f;
        #pragma unroll
        for (int m = 0; m < 4; ++m)
            #pragma unroll
            for (int reg = 0; reg < 4; ++reg) {
                float y = fmaxf(fmaf(acc[m][n][reg], Ac[m * 4 + reg], Oc[m * 4 + reg]), 0.0f);
                part = fmaf(Wc[m * 4 + reg], y, part);
            }
        red[(n * 16 + l15) * 17 + wave * 4 + quad] = part;
    }
    __syncthreads();
    if (tid < 128) {
        float z = b2[0];
        #pragma unroll
        for (int k = 0; k < 16; ++k) z += red[tid * 17 + k];
        if (p0 + tid < Np)
            out[(size_t)b * Np + p0 + tid] = 1.0f / (1.0f + expf(-z));
    }
}

// ---------------------------------------------------------------------------
extern "C" void kernel_launch(void* const* d_in, const int* in_sizes, int n_in,
                              void* d_out, int out_size, void* d_ws, size_t ws_size,
                              hipStream_t stream)
{
    const float* large  = (const float*)d_in[0];
    const float* medium = (const float*)d_in[1];
    const float* small  = (const float*)d_in[2];
    const float* search = (const float*)d_in[3];
    const float* wt  = (const float*)d_in[4];
    const float* bt  = (const float*)d_in[5];
    const float* gt  = (const float*)d_in[6];
    const float* bet = (const float*)d_in[7];
    const float* mt  = (const float*)d_in[8];
    const float* vt  = (const float*)d_in[9];
    const float* wsc = (const float*)d_in[10];
    const float* bs  = (const float*)d_in[11];
    const float* gs  = (const float*)d_in[12];
    const float* bes = (const float*)d_in[13];
    const float* ms  = (const float*)d_in[14];
    const float* vs  = (const float*)d_in[15];
    const float* w1  = (const float*)d_in[16];
    const float* b1  = (const float*)d_in[17];
    const float* g1  = (const float*)d_in[18];
    const float* be1 = (const float*)d_in[19];
    const float* m1  = (const float*)d_in[20];
    const float* v1  = (const float*)d_in[21];
    const float* w2  = (const float*)d_in[22];
    const float* b2  = (const float*)d_in[23];

    float* ws = (float*)d_ws;
    size_t off = 0;
    float* lf = ws + off; off += (size_t)64 * 256 * 49;
    float* mf = ws + off; off += (size_t)64 * 256 * 25;
    float* sf = ws + off; off += (size_t)64 * 256 * 9;
    float* sq = ws + off; off += (size_t)64 * 256 * 841;
    float* lc = ws + off; off += (size_t)64 * 256 * 729;
    float* mc = ws + off; off += (size_t)64 * 256 * 625;
    float* sc = ws + off; off += (size_t)64 * 256 * 729;

    // Aliased prep buffers (dead before corr writes lc/mc/sc):
    short* xh_s = (short*)lc;
    short* xl_s = (short*)lc + 15745024;
    short* base = (short*)sc;
    short* xh_L = base;
    short* xl_L = base + 1327104;
    short* xh_M = base + 2654208;
    short* xl_M = base + 3457024;
    short* xh_S = base + 4259840;
    short* xl_S = base + 4669440;
    short* wh_t = base + 5079040;
    short* wl_t = base + 5668864;
    short* wh_s = base + 6258688;
    short* wl_s = base + 6848512;

    dim3 blk(256);
    prep_w_split<<<dim3(128), blk, 0, stream>>>(wt,  wh_t, wl_t);
    prep_w_split<<<dim3(128), blk, 0, stream>>>(wsc, wh_s, wl_s);
    prep_x_split<<<dim3(16, 4, 64), blk, 0, stream>>>(search, xh_s, xl_s, 961);
    prep_x_split<<<dim3(2, 4, 64),  blk, 0, stream>>>(large,  xh_L, xl_L, 81);
    prep_x_split<<<dim3(1, 4, 64),  blk, 0, stream>>>(medium, xh_M, xl_M, 49);
    prep_x_split<<<dim3(1, 4, 64),  blk, 0, stream>>>(small,  xh_S, xl_S, 25);

    conv_mfma_kernel<<<dim3(1, 2, 64), blk, 0, stream>>>(xh_L, xl_L, wh_t, wl_t, bt, gt, bet, mt, vt, lf, 9, 9);
    conv_mfma_kernel<<<dim3(1, 2, 64), blk, 0, stream>>>(xh_M, xl_M, wh_t, wl_t, bt, gt, bet, mt, vt, mf, 7, 7);
    conv_mfma_kernel<<<dim3(1, 2, 64), blk, 0, stream>>>(xh_S, xl_S, wh_t, wl_t, bt, gt, bet, mt, vt, sf, 5, 5);
    conv_mfma_kernel<<<dim3(7, 2, 64), blk, 0, stream>>>(xh_s, xl_s, wh_s, wl_s, bs, gs, bes, ms, vs, sq, 31, 31);

    corr_kernel<<<dim3(64, 64), blk, 0, stream>>>(lf, mf, sf, sq, lc, mc, sc);

    float* outp = (float*)d_out;
    head_mfma_kernel<<<dim3(6, 64), blk, 0, stream>>>(lc, w1, b1, g1, be1, m1, v1, w2, b2, outp, 729);
    head_mfma_kernel<<<dim3(5, 64), blk, 0, stream>>>(mc, w1, b1, g1, be1, m1, v1, w2, b2, outp + 46656, 625);
    head_mfma_kernel<<<dim3(6, 64), blk, 0, stream>>>(sc, w1, b1, g1, be1, m1, v1, w2, b2, outp + 86656, 729);
}